// Round 5
// baseline (206.760 us; speedup 1.0000x reference)
//
#include <hip/hip_runtime.h>
#include <math.h>

#define TMAX 16384
#define MDIM 16
#define SD   2048
#define CHK  512     // number of parallel chunks
#define CLEN 32      // steps per chunk (CHK*CLEN == TMAX)
#define WUP  32      // warmup steps per chunk (boundary forgetting)
#define EROWS 32     // t-rows per emP block

typedef unsigned int  uint;
typedef unsigned short ushort;
typedef __attribute__((ext_vector_type(8))) short short8;
typedef __attribute__((ext_vector_type(4))) short short4v;
typedef __attribute__((ext_vector_type(4))) float floatx4;
typedef __attribute__((ext_vector_type(2))) uint uintx2;

// ---- DPP-based full-wave (64-lane) max ----
template<int CTRL>
__device__ __forceinline__ float fmax_dpp(float v) {
    int o = __builtin_amdgcn_update_dpp(__float_as_int(v), __float_as_int(v),
                                        CTRL, 0xf, 0xf, false);
    return fmaxf(v, __int_as_float(o));
}
__device__ __forceinline__ float waveMax64(float v) {
    v = fmax_dpp<0x111>(v);
    v = fmax_dpp<0x112>(v);
    v = fmax_dpp<0x114>(v);
    v = fmax_dpp<0x118>(v);
    v = fmax_dpp<0x142>(v);
    v = fmax_dpp<0x143>(v);
    return __int_as_float(__builtin_amdgcn_readlane(__float_as_int(v), 63));
}
__device__ __forceinline__ float waveSumF(float v) {
    #pragma unroll
    for (int o = 32; o > 0; o >>= 1) v += __shfl_xor(v, o, 64);
    return v;
}
__device__ __forceinline__ double waveSumD(double v) {
    #pragma unroll
    for (int o = 32; o > 0; o >>= 1) v += __shfl_xor(v, o, 64);
    return v;
}

// bf16 helpers (RNE emulation — bit-exact, harness-proven)
__device__ __forceinline__ short f2bfs(float f) {
    uint u = __float_as_uint(f);
    return (short)((u + 0x7FFFu + ((u >> 16) & 1u)) >> 16);
}
__device__ __forceinline__ uint pkbf(float a, float b) {
    uint ua = __float_as_uint(a), ub = __float_as_uint(b);
    ua = (ua + 0x7FFFu + ((ua >> 16) & 1u)) >> 16;
    ub = (ub + 0x7FFFu + ((ub >> 16) & 1u)) & 0xFFFF0000u;
    return ua | ub;
}
__device__ __forceinline__ short4v pk4(float a, float b, float c, float d) {
    short4v r;
    r[0] = f2bfs(a); r[1] = f2bfs(b); r[2] = f2bfs(c); r[3] = f2bfs(d);
    return r;
}
__device__ __forceinline__ float bfl(uint u) { return __uint_as_float(u << 16); }
__device__ __forceinline__ float bfh(uint u) { return __uint_as_float(u & 0xFFFF0000u); }

// K=16 bf16 MFMA
#if __has_builtin(__builtin_amdgcn_mfma_f32_16x16x16bf16_1k)
#define MFMA16(a, b, c) __builtin_amdgcn_mfma_f32_16x16x16bf16_1k(a, b, c, 0, 0, 0)
#else
__device__ __forceinline__ floatx4 mfma16_asm(short4v a, short4v b, floatx4 c) {
    asm volatile("v_mfma_f32_16x16x16_bf16 %0, %1, %2, %0\n\t"
                 "s_nop 7\n\ts_nop 7"
                 : "+v"(c) : "v"(a), "v"(b));
    return c;
}
#define MFMA16(a, b, c) mfma16_asm(a, b, c)
#endif
#define MFMA32(a, b, c) __builtin_amdgcn_mfma_f32_16x16x32_bf16(a, b, c, 0, 0, 0)

// ---- K2: fused pre-pass. 512 blocks x 512 threads x 32 t-rows each.
// 4 states/thread (llc = 64 VGPR -> 2 blocks/CU). P stores are staged in LDS
// per row-PAIR and flushed as 16B/lane global_store_dwordx4 (full write
// granules; R4's 8B/lane uint2 stores showed 2.1x WRITE + phantom FETCH
// amplification -> emP was bound at 181MB of HBM traffic).
// Slot order identical: slot o = tid*4 + j -> s = (4q+j)*128 + 16*wv + nn.
__global__ __launch_bounds__(512, 4)
void emP_kernel(const int* __restrict__ x,
                const float* __restrict__ lam1,
                const float* __restrict__ lam2,
                const float* __restrict__ lam3,
                ushort* __restrict__ P,
                float* __restrict__ SumAux) {
    __shared__ __align__(16) float red[2][8];
    __shared__ __align__(16) uint2 stg[2][512];   // 8KB row-pair staging
    __shared__ float lgtbl[32];
    __shared__ float lgred;
    const int tid = threadIdx.x, lane = tid & 63, wv = tid >> 6;
    const int q = lane >> 4, nn = lane & 15;
    const int d2 = 2 * wv + (nn >> 3);
    const int d3 = nn & 7;

    if (tid < 32) lgtbl[tid] = lgammaf((float)tid + 1.0f);
    if (tid == 0) lgred = 0.f;

    float llc[4][16], ls[4];
    #pragma unroll
    for (int j = 0; j < 4; ++j) {
        const int d1 = 4 * q + j;
        float sum = 0.f;
        #pragma unroll
        for (int m = 0; m < 16; ++m) {
            float la = lam1[d1 * 16 + m] + lam2[d2 * 16 + m] + lam3[d3 * 16 + m];
            sum += la;
            llc[j][m] = __logf(la);
        }
        ls[j] = sum;
    }
    __syncthreads();   // lgtbl + lgred ready

    const int t0 = blockIdx.x * EROWS;
    // lgamma over this block's 32 t-rows (512 ints): 1 per thread
    {
        int v = x[t0 * MDIM + tid];
        double lg = (double)lgtbl[v & 31];
        lg = waveSumD(lg);
        if (lane == 0) atomicAdd(&lgred, (float)lg);
    }

    double sumD = 0.0;
    for (int pi = 0; pi < EROWS / 2; ++pi) {
        #pragma unroll
        for (int h = 0; h < 2; ++h) {
            const int t = t0 + 2 * pi + h;
            const int* __restrict__ xr = x + t * MDIM;   // uniform -> scalar loads
            float em[4];
            float vm = -3.4e38f;
            #pragma unroll
            for (int j = 0; j < 4; ++j) {
                float d = 0.f;
                #pragma unroll
                for (int m = 0; m < 16; ++m) d = fmaf((float)xr[m], llc[j][m], d);
                em[j] = d - ls[j];
                vm = fmaxf(vm, em[j]);
            }
            vm = waveMax64(vm);
            if (lane == 0) red[h][wv] = vm;
            __syncthreads();           // red[h] ready (buffers alternate per h)
            const float4 ra = *(const float4*)&red[h][0];
            const float4 rb = *(const float4*)&red[h][4];
            float Dem = fmaxf(fmaxf(fmaxf(ra.x, ra.y), fmaxf(ra.z, ra.w)),
                              fmaxf(fmaxf(rb.x, rb.y), fmaxf(rb.z, rb.w)));
            uint2 w;
            w.x = pkbf(__expf(em[0] - Dem), __expf(em[1] - Dem));
            w.y = pkbf(__expf(em[2] - Dem), __expf(em[3] - Dem));
            stg[h][tid] = w;
            if (tid == 0) sumD += (double)Dem;
        }
        __syncthreads();               // stg[0..1] complete for this pair
        // pair-span flush: 8KB contiguous, 16B/lane fully-coalesced stores
        uint4 v = ((const uint4*)stg)[tid];
        *(uint4*)(P + (size_t)(t0 + 2 * pi) * SD + tid * 8) = v;
    }
    __syncthreads();
    if (tid == 0) atomicAdd(SumAux, (float)sumD - lgred);
}

// ---- K3: CHUNKED forward recurrence. grid = CHK blocks x 512 threads.
// Defer-rescale every 2 steps: odd steps compute per-wave max only (wa -> wmA);
// even steps apply inv = 1/max(beta_{t-1}) and accumulate log when t > bAcc.
// Exact-telescoping: logged terms telescope over the odd-index chain to
// G = log[max beta'_{tEnd-1}/max beta'_{bAcc-1}] — identical to every-step
// rescale. Range-safe: per-step shrink >= e^{-48} >> f32 min normal.
// [R4-verified: passed, absmax 0.0]
__global__ __launch_bounds__(512, 2)
void fhmm_chunk_kernel(const ushort* __restrict__ P,
                       const float* __restrict__ SumAux,
                       const float* __restrict__ logA1,
                       const float* __restrict__ logA2,
                       const float* __restrict__ logA3,
                       const float* __restrict__ logpi1,
                       const float* __restrict__ logpi2,
                       const float* __restrict__ logpi3,
                       float* __restrict__ out)
{
    __shared__ __align__(16) short c1b[2 * 2048];   // parity double buffer
    __shared__ float wmA[8];                        // odd steps write, even read
    __shared__ float sred[8];

    const int tid  = threadIdx.x;
    const int lane = tid & 63;
    const int wv   = tid >> 6;
    const int q    = lane >> 4;
    const int ml   = lane & 15;

    const int c    = blockIdx.x;
    const int tw0  = (c == 0) ? 0 : c * CLEN - WUP;
    const int tEnd = (c + 1) * CLEN;
    const int bAcc = c * CLEN;

    // S1 constants (K=16): B[k=p1=4q+j][n=d1'=ml] = exp(logA1[ml][4q+j])
    short4v bA1k;
    #pragma unroll
    for (int j = 0; j < 4; ++j)
        bA1k[j] = f2bfs(__expf(logA1[ml * 16 + 4 * q + j]));

    // S23 constants, 4 K-chunks: k' = 32jc + 8q + i -> p2 = 4jc+q, p3 = i
    const int d2p = 2 * wv + (ml >> 3);
    const int d3p = ml & 7;
    short8 bK[4];
    #pragma unroll
    for (int jc = 0; jc < 4; ++jc)
        #pragma unroll
        for (int i = 0; i < 8; ++i)
            bK[jc][i] = f2bfs(__expf(logA2[d2p * 16 + 4 * jc + q] + logA3[d3p * 8 + i]));

    // S1 D write offset into c1b[par]  [R9/R10-verified]
    const int oS1w = ml * 128 + ((((2 * wv + (q >> 1)) ^ ml) & 15) << 3) + 4 * (q & 1);
    // S23 A-frag offsets [R9/R10-verified]
    int o23[4];
    #pragma unroll
    for (int jc = 0; jc < 4; ++jc)
        o23[jc] = ml * 128 + ((((4 * jc + q) ^ ml) & 15) << 3);

    // ---- init beta at t = tw0 ----
    double OFF = 0.0;
    float nu0, nu1, nu2, nu3;
    {
        uintx2 p0 = *(const uintx2*)(P + (size_t)tw0 * SD + tid * 4);
        if (c == 0) {   // exact: beta_0 = P_0 * pi
            float lp23 = logpi2[d2p] + logpi3[d3p];
            nu0 = bfl(p0.x) * __expf(logpi1[4 * q + 0] + lp23);
            nu1 = bfh(p0.x) * __expf(logpi1[4 * q + 1] + lp23);
            nu2 = bfl(p0.y) * __expf(logpi1[4 * q + 2] + lp23);
            nu3 = bfh(p0.y) * __expf(logpi1[4 * q + 3] + lp23);
        } else {        // warm-start: beta = P row (arbitrary positive scale)
            nu0 = bfl(p0.x); nu1 = bfh(p0.x);
            nu2 = bfl(p0.y); nu3 = bfh(p0.y);
        }
    }

    // 2-deep P prefetch
    uintx2 Pb0 = *(const uintx2*)(P + (size_t)(tw0 + 1) * SD + tid * 4);
    uintx2 Pb1 = *(const uintx2*)(P + (size_t)(tw0 + 2) * SD + tid * 4);

// One forward step. RESC: compile-time (apply inv + maybe log); on !RESC steps
// compute the per-wave max (wa) feeding the next RESC step. ACCF: runtime
// uniform bool (t > bAcc) gating OFF accumulation.
#define FSTEP(T, RESC, ACCF)                                                    \
{                                                                               \
    const int par = (T) & 1;                                                    \
    short* c1cur = c1b + (par << 11);                                           \
    {   /* Stage 1 from registers */                                            \
        short4v af = pk4(nu0, nu1, nu2, nu3);                                   \
        floatx4 s1 = {0.f, 0.f, 0.f, 0.f};                                      \
        s1 = MFMA16(af, bA1k, s1);                                              \
        ((uintx2*)(c1cur + oS1w))[0] =                                          \
            (uintx2){pkbf(s1[0], s1[1]), pkbf(s1[2], s1[3])};                   \
    }                                                                           \
    __syncthreads();                                                            \
    const int tn = ((T) + 2 < TMAX) ? (T) + 2 : TMAX - 1;                       \
    uintx2 Pb2 = *(const uintx2*)(P + (size_t)tn * SD + tid * 4);               \
    float inv = 1.f;                                                            \
    if (RESC) {                                                                 \
        float mp = waveMax64(wmA[lane & 7]);                                    \
        float mg = fmaxf(mp, 1e-30f);                                           \
        inv = __builtin_amdgcn_rcpf(mg);                                        \
        if ((ACCF) && tid == 0) OFF += (double)__logf(mg);                      \
    }                                                                           \
    {   /* Stage 2+3 fused */                                                   \
        floatx4 a0 = {0.f, 0.f, 0.f, 0.f};                                      \
        floatx4 a1 = {0.f, 0.f, 0.f, 0.f};                                      \
        a0 = MFMA32(*(const short8*)(c1cur + o23[0]), bK[0], a0);               \
        a1 = MFMA32(*(const short8*)(c1cur + o23[1]), bK[1], a1);               \
        a0 = MFMA32(*(const short8*)(c1cur + o23[2]), bK[2], a0);               \
        a1 = MFMA32(*(const short8*)(c1cur + o23[3]), bK[3], a1);               \
        floatx4 acc = a0 + a1;                                                  \
        if (RESC) {                                                             \
            nu0 = bfl(Pb0.x) * acc[0] * inv;                                    \
            nu1 = bfh(Pb0.x) * acc[1] * inv;                                    \
            nu2 = bfl(Pb0.y) * acc[2] * inv;                                    \
            nu3 = bfh(Pb0.y) * acc[3] * inv;                                    \
        } else {                                                                \
            nu0 = bfl(Pb0.x) * acc[0];                                          \
            nu1 = bfh(Pb0.x) * acc[1];                                          \
            nu2 = bfl(Pb0.y) * acc[2];                                          \
            nu3 = bfh(Pb0.y) * acc[3];                                          \
            float wa = waveMax64(fmaxf(fmaxf(nu0, nu1), fmaxf(nu2, nu3)));      \
            if (lane == 0) wmA[wv] = wa;                                        \
        }                                                                       \
    }                                                                           \
    Pb0 = Pb1; Pb1 = Pb2;                                                       \
}

    // steps tw0+1 .. tEnd-1; first and last are odd (tw0, tEnd, bAcc all even)
    FSTEP(tw0 + 1, false, false);
    for (int te = tw0 + 2; te < tEnd; te += 2) {
        const bool accf = te > bAcc;
        FSTEP(te, true, accf);
        FSTEP(te + 1, false, false);
    }
#undef FSTEP

    __syncthreads();

    if (c == CHK - 1) {
        float su = waveSumF(nu0 + nu1 + nu2 + nu3);
        if (lane == 0) sred[wv] = su;
        __syncthreads();
        if (tid == 0) {
            float tot = 0.f;
            #pragma unroll
            for (int i = 0; i < 8; ++i) tot += sred[i];
            OFF += (double)__logf(tot);
            atomicAdd(out, (float)OFF);
        }
    } else {
        if (tid == 0) {
            float mp = wmA[0];
            #pragma unroll
            for (int i = 1; i < 8; ++i) mp = fmaxf(mp, wmA[i]);
            OFF += (double)__logf(fmaxf(mp, 1e-30f));
            if (c == 0) OFF += (double)SumAux[0];
            atomicAdd(out, (float)OFF);
        }
    }
}

extern "C" void kernel_launch(void* const* d_in, const int* in_sizes, int n_in,
                              void* d_out, int out_size, void* d_ws, size_t ws_size,
                              hipStream_t stream) {
    const int*   x      = (const int*)  d_in[0];
    const float* lam1   = (const float*)d_in[1];
    const float* lam2   = (const float*)d_in[2];
    const float* lam3   = (const float*)d_in[3];
    const float* logA1  = (const float*)d_in[4];
    const float* logA2  = (const float*)d_in[5];
    const float* logA3  = (const float*)d_in[6];
    const float* logpi1 = (const float*)d_in[7];
    const float* logpi2 = (const float*)d_in[8];
    const float* logpi3 = (const float*)d_in[9];
    float* out = (float*)d_out;

    // ws: [SumAux (256B)] [P_perm: TMAX*2048*2B = 64MB]
    float*  SumAux = (float*)d_ws;
    ushort* P      = (ushort*)((char*)d_ws + 256);

    hipMemsetAsync(out, 0, sizeof(float), stream);
    hipMemsetAsync(SumAux, 0, sizeof(float), stream);
    emP_kernel <<<dim3(TMAX / EROWS), dim3(512), 0, stream>>>(x, lam1, lam2, lam3, P, SumAux);
    fhmm_chunk_kernel<<<dim3(CHK), dim3(512), 0, stream>>>(
        P, SumAux, logA1, logA2, logA3, logpi1, logpi2, logpi3, out);
}

// Round 6
// 201.228 us; speedup vs baseline: 1.0275x; 1.0275x over previous
//
#include <hip/hip_runtime.h>
#include <math.h>

#define TMAX 16384
#define MDIM 16
#define SD   2048
#define CHK  512     // number of parallel chunks
#define CLEN 32      // steps per chunk (CHK*CLEN == TMAX)
#define WUP  32      // warmup steps per chunk (boundary forgetting)
#define EROWS 32     // t-rows per emP block

typedef unsigned int  uint;
typedef unsigned short ushort;
typedef __attribute__((ext_vector_type(8))) short short8;
typedef __attribute__((ext_vector_type(4))) short short4v;
typedef __attribute__((ext_vector_type(4))) float floatx4;
typedef __attribute__((ext_vector_type(2))) uint uintx2;

// ---- DPP-based full-wave (64-lane) max ----
template<int CTRL>
__device__ __forceinline__ float fmax_dpp(float v) {
    int o = __builtin_amdgcn_update_dpp(__float_as_int(v), __float_as_int(v),
                                        CTRL, 0xf, 0xf, false);
    return fmaxf(v, __int_as_float(o));
}
__device__ __forceinline__ float waveMax64(float v) {
    v = fmax_dpp<0x111>(v);
    v = fmax_dpp<0x112>(v);
    v = fmax_dpp<0x114>(v);
    v = fmax_dpp<0x118>(v);
    v = fmax_dpp<0x142>(v);
    v = fmax_dpp<0x143>(v);
    return __int_as_float(__builtin_amdgcn_readlane(__float_as_int(v), 63));
}
__device__ __forceinline__ float waveSumF(float v) {
    #pragma unroll
    for (int o = 32; o > 0; o >>= 1) v += __shfl_xor(v, o, 64);
    return v;
}
__device__ __forceinline__ double waveSumD(double v) {
    #pragma unroll
    for (int o = 32; o > 0; o >>= 1) v += __shfl_xor(v, o, 64);
    return v;
}

// bf16 helpers (RNE emulation — bit-exact, harness-proven)
__device__ __forceinline__ short f2bfs(float f) {
    uint u = __float_as_uint(f);
    return (short)((u + 0x7FFFu + ((u >> 16) & 1u)) >> 16);
}
__device__ __forceinline__ uint pkbf(float a, float b) {
    uint ua = __float_as_uint(a), ub = __float_as_uint(b);
    ua = (ua + 0x7FFFu + ((ua >> 16) & 1u)) >> 16;
    ub = (ub + 0x7FFFu + ((ub >> 16) & 1u)) & 0xFFFF0000u;
    return ua | ub;
}
__device__ __forceinline__ short4v pk4(float a, float b, float c, float d) {
    short4v r;
    r[0] = f2bfs(a); r[1] = f2bfs(b); r[2] = f2bfs(c); r[3] = f2bfs(d);
    return r;
}
__device__ __forceinline__ float bfl(uint u) { return __uint_as_float(u << 16); }
__device__ __forceinline__ float bfh(uint u) { return __uint_as_float(u & 0xFFFF0000u); }

// K=16 bf16 MFMA
#if __has_builtin(__builtin_amdgcn_mfma_f32_16x16x16bf16_1k)
#define MFMA16(a, b, c) __builtin_amdgcn_mfma_f32_16x16x16bf16_1k(a, b, c, 0, 0, 0)
#else
__device__ __forceinline__ floatx4 mfma16_asm(short4v a, short4v b, floatx4 c) {
    asm volatile("v_mfma_f32_16x16x16_bf16 %0, %1, %2, %0\n\t"
                 "s_nop 7\n\ts_nop 7"
                 : "+v"(c) : "v"(a), "v"(b));
    return c;
}
#define MFMA16(a, b, c) mfma16_asm(a, b, c)
#endif
#define MFMA32(a, b, c) __builtin_amdgcn_mfma_f32_16x16x32_bf16(a, b, c, 0, 0, 0)

// ---- K2: TWO-PASS fused pre-pass. 512 blocks x 512 threads x 32 t-rows.
// R4/R5 post-mortem: per-row __syncthreads drains all outstanding stores
// (vmcnt(0)) -> kernel alternated tiny compute with store drains, neither
// pipe saturated (VALU 45%, EA 2.1TB/s). Two-pass removes in-loop barriers:
//   pass 1: per-row wave maxima only (waveMax64 -> wmx[ti][wv], wave-owned
//           columns, NO barrier). One barrier. Lanes 0-31 reduce -> DemS[32].
//           One barrier.
//   pass 2: recompute em (bit-identical FMA sequence => exp(em-Dem) <= 1
//           exactly), exp, pack, direct uint2 stores, ZERO barriers ->
//           stores stream and overlap compute.
// Slot order unchanged: slot o = tid*4 + j -> s = (4q+j)*128 + 16*wv + nn.
// Also: block 0 zeroes `out` (kernel-boundary ordered before fhmm's atomics);
// per-block partial (sumD - lgamma) -> SumAuxArr[block] plain store (no
// memset / no global atomic needed).
__global__ __launch_bounds__(512, 4)
void emP_kernel(const int* __restrict__ x,
                const float* __restrict__ lam1,
                const float* __restrict__ lam2,
                const float* __restrict__ lam3,
                ushort* __restrict__ P,
                float* __restrict__ SumAuxArr,
                float* __restrict__ out) {
    __shared__ float wmx[EROWS][8];
    __shared__ float DemS[EROWS];
    __shared__ float lgtbl[32];
    __shared__ float lgred;
    const int tid = threadIdx.x, lane = tid & 63, wv = tid >> 6;
    const int q = lane >> 4, nn = lane & 15;
    const int d2 = 2 * wv + (nn >> 3);
    const int d3 = nn & 7;

    if (tid < 32) lgtbl[tid] = lgammaf((float)tid + 1.0f);
    if (tid == 0) lgred = 0.f;

    float llc[4][16], ls[4];
    #pragma unroll
    for (int j = 0; j < 4; ++j) {
        const int d1 = 4 * q + j;
        float sum = 0.f;
        #pragma unroll
        for (int m = 0; m < 16; ++m) {
            float la = lam1[d1 * 16 + m] + lam2[d2 * 16 + m] + lam3[d3 * 16 + m];
            sum += la;
            llc[j][m] = __logf(la);
        }
        ls[j] = sum;
    }
    __syncthreads();   // lgtbl + lgred ready

    const int t0 = blockIdx.x * EROWS;
    // lgamma over this block's 32 t-rows (512 ints): 1 per thread
    {
        int v = x[t0 * MDIM + tid];
        double lg = (double)lgtbl[v & 31];
        lg = waveSumD(lg);
        if (lane == 0) atomicAdd(&lgred, (float)lg);
    }

    // ---- pass 1: per-row global max (no in-loop barriers) ----
    for (int ti = 0; ti < EROWS; ++ti) {
        const int* __restrict__ xr = x + (t0 + ti) * MDIM;  // uniform -> scalar
        float vm = -3.4e38f;
        #pragma unroll
        for (int j = 0; j < 4; ++j) {
            float d = 0.f;
            #pragma unroll
            for (int m = 0; m < 16; ++m) d = fmaf((float)xr[m], llc[j][m], d);
            vm = fmaxf(vm, d - ls[j]);
        }
        vm = waveMax64(vm);
        if (lane == 0) wmx[ti][wv] = vm;     // wave-owned column, no race
    }
    __syncthreads();                          // all wmx published (+ lgred done)
    if (tid < 32) {
        float m = wmx[tid][0];
        #pragma unroll
        for (int i = 1; i < 8; ++i) m = fmaxf(m, wmx[tid][i]);
        DemS[tid] = m;
    }
    __syncthreads();                          // DemS ready

    // ---- pass 2: recompute em, exp, pack, stream stores (no barriers) ----
    for (int ti = 0; ti < EROWS; ++ti) {
        const int t = t0 + ti;
        const int* __restrict__ xr = x + t * MDIM;
        float em[4];
        #pragma unroll
        for (int j = 0; j < 4; ++j) {
            float d = 0.f;
            #pragma unroll
            for (int m = 0; m < 16; ++m) d = fmaf((float)xr[m], llc[j][m], d);
            em[j] = d - ls[j];
        }
        const float Dem = DemS[ti];
        uint2 w;
        w.x = pkbf(__expf(em[0] - Dem), __expf(em[1] - Dem));
        w.y = pkbf(__expf(em[2] - Dem), __expf(em[3] - Dem));
        *(uint2*)(P + (size_t)t * SD + tid * 4) = w;
    }

    if (tid == 0) {
        double sumD = 0.0;
        #pragma unroll
        for (int i = 0; i < EROWS; ++i) sumD += (double)DemS[i];
        SumAuxArr[blockIdx.x] = (float)sumD - lgred;
        if (blockIdx.x == 0) out[0] = 0.f;   // ordered before fhmm (stream)
    }
}

// ---- K3: CHUNKED forward recurrence. grid = CHK blocks x 512 threads.
// Defer-rescale every 2 steps [R4-verified: passed, absmax 0.0].
// Chunk 0 additionally reduces SumAuxArr[512] (replaces memset+atomic scheme).
__global__ __launch_bounds__(512, 2)
void fhmm_chunk_kernel(const ushort* __restrict__ P,
                       const float* __restrict__ SumAuxArr,
                       const float* __restrict__ logA1,
                       const float* __restrict__ logA2,
                       const float* __restrict__ logA3,
                       const float* __restrict__ logpi1,
                       const float* __restrict__ logpi2,
                       const float* __restrict__ logpi3,
                       float* __restrict__ out)
{
    __shared__ __align__(16) short c1b[2 * 2048];   // parity double buffer
    __shared__ float wmA[8];                        // odd steps write, even read
    __shared__ float sred[8];
    __shared__ float saux8[8];

    const int tid  = threadIdx.x;
    const int lane = tid & 63;
    const int wv   = tid >> 6;
    const int q    = lane >> 4;
    const int ml   = lane & 15;

    const int c    = blockIdx.x;
    const int tw0  = (c == 0) ? 0 : c * CLEN - WUP;
    const int tEnd = (c + 1) * CLEN;
    const int bAcc = c * CLEN;

    // S1 constants (K=16): B[k=p1=4q+j][n=d1'=ml] = exp(logA1[ml][4q+j])
    short4v bA1k;
    #pragma unroll
    for (int j = 0; j < 4; ++j)
        bA1k[j] = f2bfs(__expf(logA1[ml * 16 + 4 * q + j]));

    // S23 constants, 4 K-chunks: k' = 32jc + 8q + i -> p2 = 4jc+q, p3 = i
    const int d2p = 2 * wv + (ml >> 3);
    const int d3p = ml & 7;
    short8 bK[4];
    #pragma unroll
    for (int jc = 0; jc < 4; ++jc)
        #pragma unroll
        for (int i = 0; i < 8; ++i)
            bK[jc][i] = f2bfs(__expf(logA2[d2p * 16 + 4 * jc + q] + logA3[d3p * 8 + i]));

    // S1 D write offset into c1b[par]  [R9/R10-verified]
    const int oS1w = ml * 128 + ((((2 * wv + (q >> 1)) ^ ml) & 15) << 3) + 4 * (q & 1);
    // S23 A-frag offsets [R9/R10-verified]
    int o23[4];
    #pragma unroll
    for (int jc = 0; jc < 4; ++jc)
        o23[jc] = ml * 128 + ((((4 * jc + q) ^ ml) & 15) << 3);

    // chunk 0: reduce the 512 per-block emission partials (published by the
    // first FSTEP's barrier; consumed only in the tail)
    if (c == 0) {
        float sx = waveSumF(SumAuxArr[tid]);
        if (lane == 0) saux8[wv] = sx;
    }

    // ---- init beta at t = tw0 ----
    double OFF = 0.0;
    float nu0, nu1, nu2, nu3;
    {
        uintx2 p0 = *(const uintx2*)(P + (size_t)tw0 * SD + tid * 4);
        if (c == 0) {   // exact: beta_0 = P_0 * pi
            float lp23 = logpi2[d2p] + logpi3[d3p];
            nu0 = bfl(p0.x) * __expf(logpi1[4 * q + 0] + lp23);
            nu1 = bfh(p0.x) * __expf(logpi1[4 * q + 1] + lp23);
            nu2 = bfl(p0.y) * __expf(logpi1[4 * q + 2] + lp23);
            nu3 = bfh(p0.y) * __expf(logpi1[4 * q + 3] + lp23);
        } else {        // warm-start: beta = P row (arbitrary positive scale)
            nu0 = bfl(p0.x); nu1 = bfh(p0.x);
            nu2 = bfl(p0.y); nu3 = bfh(p0.y);
        }
    }

    // 2-deep P prefetch
    uintx2 Pb0 = *(const uintx2*)(P + (size_t)(tw0 + 1) * SD + tid * 4);
    uintx2 Pb1 = *(const uintx2*)(P + (size_t)(tw0 + 2) * SD + tid * 4);

// One forward step. RESC: compile-time (apply inv + maybe log); on !RESC steps
// compute the per-wave max (wa) feeding the next RESC step. ACCF: runtime
// uniform bool (t > bAcc) gating OFF accumulation.
#define FSTEP(T, RESC, ACCF)                                                    \
{                                                                               \
    const int par = (T) & 1;                                                    \
    short* c1cur = c1b + (par << 11);                                           \
    {   /* Stage 1 from registers */                                            \
        short4v af = pk4(nu0, nu1, nu2, nu3);                                   \
        floatx4 s1 = {0.f, 0.f, 0.f, 0.f};                                      \
        s1 = MFMA16(af, bA1k, s1);                                              \
        ((uintx2*)(c1cur + oS1w))[0] =                                          \
            (uintx2){pkbf(s1[0], s1[1]), pkbf(s1[2], s1[3])};                   \
    }                                                                           \
    __syncthreads();                                                            \
    const int tn = ((T) + 2 < TMAX) ? (T) + 2 : TMAX - 1;                       \
    uintx2 Pb2 = *(const uintx2*)(P + (size_t)tn * SD + tid * 4);               \
    float inv = 1.f;                                                            \
    if (RESC) {                                                                 \
        float mp = waveMax64(wmA[lane & 7]);                                    \
        float mg = fmaxf(mp, 1e-30f);                                           \
        inv = __builtin_amdgcn_rcpf(mg);                                        \
        if ((ACCF) && tid == 0) OFF += (double)__logf(mg);                      \
    }                                                                           \
    {   /* Stage 2+3 fused */                                                   \
        floatx4 a0 = {0.f, 0.f, 0.f, 0.f};                                      \
        floatx4 a1 = {0.f, 0.f, 0.f, 0.f};                                      \
        a0 = MFMA32(*(const short8*)(c1cur + o23[0]), bK[0], a0);               \
        a1 = MFMA32(*(const short8*)(c1cur + o23[1]), bK[1], a1);               \
        a0 = MFMA32(*(const short8*)(c1cur + o23[2]), bK[2], a0);               \
        a1 = MFMA32(*(const short8*)(c1cur + o23[3]), bK[3], a1);               \
        floatx4 acc = a0 + a1;                                                  \
        if (RESC) {                                                             \
            nu0 = bfl(Pb0.x) * acc[0] * inv;                                    \
            nu1 = bfh(Pb0.x) * acc[1] * inv;                                    \
            nu2 = bfl(Pb0.y) * acc[2] * inv;                                    \
            nu3 = bfh(Pb0.y) * acc[3] * inv;                                    \
        } else {                                                                \
            nu0 = bfl(Pb0.x) * acc[0];                                          \
            nu1 = bfh(Pb0.x) * acc[1];                                          \
            nu2 = bfl(Pb0.y) * acc[2];                                          \
            nu3 = bfh(Pb0.y) * acc[3];                                          \
            float wa = waveMax64(fmaxf(fmaxf(nu0, nu1), fmaxf(nu2, nu3)));      \
            if (lane == 0) wmA[wv] = wa;                                        \
        }                                                                       \
    }                                                                           \
    Pb0 = Pb1; Pb1 = Pb2;                                                       \
}

    // steps tw0+1 .. tEnd-1; first and last are odd (tw0, tEnd, bAcc all even)
    FSTEP(tw0 + 1, false, false);
    for (int te = tw0 + 2; te < tEnd; te += 2) {
        const bool accf = te > bAcc;
        FSTEP(te, true, accf);
        FSTEP(te + 1, false, false);
    }
#undef FSTEP

    __syncthreads();

    if (c == CHK - 1) {
        float su = waveSumF(nu0 + nu1 + nu2 + nu3);
        if (lane == 0) sred[wv] = su;
        __syncthreads();
        if (tid == 0) {
            float tot = 0.f;
            #pragma unroll
            for (int i = 0; i < 8; ++i) tot += sred[i];
            OFF += (double)__logf(tot);
            atomicAdd(out, (float)OFF);
        }
    } else {
        if (tid == 0) {
            float mp = wmA[0];
            #pragma unroll
            for (int i = 1; i < 8; ++i) mp = fmaxf(mp, wmA[i]);
            OFF += (double)__logf(fmaxf(mp, 1e-30f));
            if (c == 0) {
                float sa = 0.f;
                #pragma unroll
                for (int i = 0; i < 8; ++i) sa += saux8[i];
                OFF += (double)sa;
            }
            atomicAdd(out, (float)OFF);
        }
    }
}

extern "C" void kernel_launch(void* const* d_in, const int* in_sizes, int n_in,
                              void* d_out, int out_size, void* d_ws, size_t ws_size,
                              hipStream_t stream) {
    const int*   x      = (const int*)  d_in[0];
    const float* lam1   = (const float*)d_in[1];
    const float* lam2   = (const float*)d_in[2];
    const float* lam3   = (const float*)d_in[3];
    const float* logA1  = (const float*)d_in[4];
    const float* logA2  = (const float*)d_in[5];
    const float* logA3  = (const float*)d_in[6];
    const float* logpi1 = (const float*)d_in[7];
    const float* logpi2 = (const float*)d_in[8];
    const float* logpi3 = (const float*)d_in[9];
    float* out = (float*)d_out;

    // ws: [SumAuxArr: 512 floats (2KB), pad to 4KB] [P_perm: TMAX*2048*2B = 64MB]
    float*  SumAuxArr = (float*)d_ws;
    ushort* P         = (ushort*)((char*)d_ws + 4096);

    // no memsets: out zeroed by emP block 0; SumAuxArr fully overwritten by
    // emP plain stores (one per block, 512 blocks == array size).
    emP_kernel <<<dim3(TMAX / EROWS), dim3(512), 0, stream>>>(
        x, lam1, lam2, lam3, P, SumAuxArr, out);
    fhmm_chunk_kernel<<<dim3(CHK), dim3(512), 0, stream>>>(
        P, SumAuxArr, logA1, logA2, logA3, logpi1, logpi2, logpi3, out);
}

// Round 7
// 159.639 us; speedup vs baseline: 1.2952x; 1.2605x over previous
//
#include <hip/hip_runtime.h>
#include <math.h>

#define TMAX 16384
#define MDIM 16
#define SD   2048
#define CHK  512     // number of parallel chunks
#define CLEN 32      // steps per chunk (CHK*CLEN == TMAX)
#define WUP  32      // warmup steps per chunk (boundary forgetting)
#define EROWS 32     // t-rows per emP block

typedef unsigned int  uint;
typedef unsigned short ushort;
typedef __attribute__((ext_vector_type(8))) short short8;
typedef __attribute__((ext_vector_type(4))) short short4v;
typedef __attribute__((ext_vector_type(4))) float floatx4;
typedef __attribute__((ext_vector_type(2))) uint uintx2;

// ---- DPP-based full-wave (64-lane) max ----
template<int CTRL>
__device__ __forceinline__ float fmax_dpp(float v) {
    int o = __builtin_amdgcn_update_dpp(__float_as_int(v), __float_as_int(v),
                                        CTRL, 0xf, 0xf, false);
    return fmaxf(v, __int_as_float(o));
}
__device__ __forceinline__ float waveMax64(float v) {
    v = fmax_dpp<0x111>(v);
    v = fmax_dpp<0x112>(v);
    v = fmax_dpp<0x114>(v);
    v = fmax_dpp<0x118>(v);
    v = fmax_dpp<0x142>(v);
    v = fmax_dpp<0x143>(v);
    return __int_as_float(__builtin_amdgcn_readlane(__float_as_int(v), 63));
}
__device__ __forceinline__ float waveSumF(float v) {
    #pragma unroll
    for (int o = 32; o > 0; o >>= 1) v += __shfl_xor(v, o, 64);
    return v;
}
__device__ __forceinline__ double waveSumD(double v) {
    #pragma unroll
    for (int o = 32; o > 0; o >>= 1) v += __shfl_xor(v, o, 64);
    return v;
}

// bf16 helpers (RNE emulation — bit-exact, harness-proven)
__device__ __forceinline__ short f2bfs(float f) {
    uint u = __float_as_uint(f);
    return (short)((u + 0x7FFFu + ((u >> 16) & 1u)) >> 16);
}
__device__ __forceinline__ uint pkbf(float a, float b) {
    uint ua = __float_as_uint(a), ub = __float_as_uint(b);
    ua = (ua + 0x7FFFu + ((ua >> 16) & 1u)) >> 16;
    ub = (ub + 0x7FFFu + ((ub >> 16) & 1u)) & 0xFFFF0000u;
    return ua | ub;
}
__device__ __forceinline__ short4v pk4(float a, float b, float c, float d) {
    short4v r;
    r[0] = f2bfs(a); r[1] = f2bfs(b); r[2] = f2bfs(c); r[3] = f2bfs(d);
    return r;
}
__device__ __forceinline__ float bfl(uint u) { return __uint_as_float(u << 16); }
__device__ __forceinline__ float bfh(uint u) { return __uint_as_float(u & 0xFFFF0000u); }

// K=16 bf16 MFMA
#if __has_builtin(__builtin_amdgcn_mfma_f32_16x16x16bf16_1k)
#define MFMA16(a, b, c) __builtin_amdgcn_mfma_f32_16x16x16bf16_1k(a, b, c, 0, 0, 0)
#else
__device__ __forceinline__ floatx4 mfma16_asm(short4v a, short4v b, floatx4 c) {
    asm volatile("v_mfma_f32_16x16x16_bf16 %0, %1, %2, %0\n\t"
                 "s_nop 7\n\ts_nop 7"
                 : "+v"(c) : "v"(a), "v"(b));
    return c;
}
#define MFMA16(a, b, c) mfma16_asm(a, b, c)
#endif
#define MFMA32(a, b, c) __builtin_amdgcn_mfma_f32_16x16x32_bf16(a, b, c, 0, 0, 0)

// ---- K2: SINGLE-PASS em-in-registers pre-pass. 512 blocks x 512 threads.
// R6 post-mortem: two-pass removed barriers but DOUBLED the 536M-FMA em
// computation (VALU 45->63%, dur unchanged). This version computes em ONCE
// and keeps em[32][4] (128 VGPR) live across the Dem reduction:
//   pass 1: em + per-row wave maxima (no in-loop barriers)
//   [barrier] tid<32 reduce wmx -> DemS[32] [barrier]
//   pass 2: exp(em-Dem) from REGISTERS, pack, streamed uint2 stores.
// __launch_bounds__(512,2): 256-VGPR budget (em 128 + llc 64 + misc), kills
// any scratch pressure. x->float hoisted to LDS (reuses the lgamma load).
// FMA order identical to R4/R6 -> em/Dem/P bit-identical.
// Slot order unchanged: slot o = tid*4 + j -> s = (4q+j)*128 + 16*wv + nn.
__global__ __launch_bounds__(512, 2)
void emP_kernel(const int* __restrict__ x,
                const float* __restrict__ lam1,
                const float* __restrict__ lam2,
                const float* __restrict__ lam3,
                ushort* __restrict__ P,
                float* __restrict__ SumAuxArr,
                float* __restrict__ out) {
    __shared__ float wmx[EROWS][8];
    __shared__ float DemS[EROWS];
    __shared__ float lgtbl[32];
    __shared__ __align__(16) float xfs[EROWS * MDIM];   // 512 floats
    __shared__ float lgred;
    const int tid = threadIdx.x, lane = tid & 63, wv = tid >> 6;
    const int q = lane >> 4, nn = lane & 15;
    const int d2 = 2 * wv + (nn >> 3);
    const int d3 = nn & 7;

    if (tid < 32) lgtbl[tid] = lgammaf((float)tid + 1.0f);
    if (tid == 0) lgred = 0.f;

    float llc[4][16], ls[4];
    #pragma unroll
    for (int j = 0; j < 4; ++j) {
        const int d1 = 4 * q + j;
        float sum = 0.f;
        #pragma unroll
        for (int m = 0; m < 16; ++m) {
            float la = lam1[d1 * 16 + m] + lam2[d2 * 16 + m] + lam3[d3 * 16 + m];
            sum += la;
            llc[j][m] = __logf(la);
        }
        ls[j] = sum;
    }

    const int t0 = blockIdx.x * EROWS;
    // one x element per thread: feeds BOTH the float table and the lgamma sum
    const int xv = x[t0 * MDIM + tid];
    xfs[tid] = (float)xv;
    __syncthreads();   // lgtbl + lgred + xfs ready
    {
        double lg = (double)lgtbl[xv & 31];
        lg = waveSumD(lg);
        if (lane == 0) atomicAdd(&lgred, (float)lg);
    }

    // ---- pass 1: em (kept in registers) + per-row wave maxima ----
    float em[EROWS][4];
    #pragma unroll
    for (int ti = 0; ti < EROWS; ++ti) {
        float xr[16];
        *(float4*)&xr[0]  = *(const float4*)&xfs[ti * 16 + 0];
        *(float4*)&xr[4]  = *(const float4*)&xfs[ti * 16 + 4];
        *(float4*)&xr[8]  = *(const float4*)&xfs[ti * 16 + 8];
        *(float4*)&xr[12] = *(const float4*)&xfs[ti * 16 + 12];
        float vm = -3.4e38f;
        #pragma unroll
        for (int j = 0; j < 4; ++j) {
            float d = 0.f;
            #pragma unroll
            for (int m = 0; m < 16; ++m) d = fmaf(xr[m], llc[j][m], d);
            em[ti][j] = d - ls[j];
            vm = fmaxf(vm, em[ti][j]);
        }
        vm = waveMax64(vm);
        if (lane == 0) wmx[ti][wv] = vm;     // wave-owned column, no race
    }
    __syncthreads();                          // all wmx published (+ lgred done)
    if (tid < 32) {
        float m = wmx[tid][0];
        #pragma unroll
        for (int i = 1; i < 8; ++i) m = fmaxf(m, wmx[tid][i]);
        DemS[tid] = m;
    }
    __syncthreads();                          // DemS ready

    // ---- pass 2: exp from registers, pack, streamed stores (no barriers) ----
    #pragma unroll
    for (int ti = 0; ti < EROWS; ++ti) {
        const float Dem = DemS[ti];
        uint2 w;
        w.x = pkbf(__expf(em[ti][0] - Dem), __expf(em[ti][1] - Dem));
        w.y = pkbf(__expf(em[ti][2] - Dem), __expf(em[ti][3] - Dem));
        *(uint2*)(P + (size_t)(t0 + ti) * SD + tid * 4) = w;
    }

    if (tid == 0) {
        double sumD = 0.0;
        #pragma unroll
        for (int i = 0; i < EROWS; ++i) sumD += (double)DemS[i];
        SumAuxArr[blockIdx.x] = (float)sumD - lgred;
        if (blockIdx.x == 0) out[0] = 0.f;   // ordered before fhmm (stream)
    }
}

// ---- K3: CHUNKED forward recurrence. grid = CHK blocks x 512 threads.
// Defer-rescale every 2 steps [R4-verified: passed, absmax 0.0].
// Chunk 0 additionally reduces SumAuxArr[512] (replaces memset+atomic scheme).
__global__ __launch_bounds__(512, 2)
void fhmm_chunk_kernel(const ushort* __restrict__ P,
                       const float* __restrict__ SumAuxArr,
                       const float* __restrict__ logA1,
                       const float* __restrict__ logA2,
                       const float* __restrict__ logA3,
                       const float* __restrict__ logpi1,
                       const float* __restrict__ logpi2,
                       const float* __restrict__ logpi3,
                       float* __restrict__ out)
{
    __shared__ __align__(16) short c1b[2 * 2048];   // parity double buffer
    __shared__ float wmA[8];                        // odd steps write, even read
    __shared__ float sred[8];
    __shared__ float saux8[8];

    const int tid  = threadIdx.x;
    const int lane = tid & 63;
    const int wv   = tid >> 6;
    const int q    = lane >> 4;
    const int ml   = lane & 15;

    const int c    = blockIdx.x;
    const int tw0  = (c == 0) ? 0 : c * CLEN - WUP;
    const int tEnd = (c + 1) * CLEN;
    const int bAcc = c * CLEN;

    // S1 constants (K=16): B[k=p1=4q+j][n=d1'=ml] = exp(logA1[ml][4q+j])
    short4v bA1k;
    #pragma unroll
    for (int j = 0; j < 4; ++j)
        bA1k[j] = f2bfs(__expf(logA1[ml * 16 + 4 * q + j]));

    // S23 constants, 4 K-chunks: k' = 32jc + 8q + i -> p2 = 4jc+q, p3 = i
    const int d2p = 2 * wv + (ml >> 3);
    const int d3p = ml & 7;
    short8 bK[4];
    #pragma unroll
    for (int jc = 0; jc < 4; ++jc)
        #pragma unroll
        for (int i = 0; i < 8; ++i)
            bK[jc][i] = f2bfs(__expf(logA2[d2p * 16 + 4 * jc + q] + logA3[d3p * 8 + i]));

    // S1 D write offset into c1b[par]  [R9/R10-verified]
    const int oS1w = ml * 128 + ((((2 * wv + (q >> 1)) ^ ml) & 15) << 3) + 4 * (q & 1);
    // S23 A-frag offsets [R9/R10-verified]
    int o23[4];
    #pragma unroll
    for (int jc = 0; jc < 4; ++jc)
        o23[jc] = ml * 128 + ((((4 * jc + q) ^ ml) & 15) << 3);

    // chunk 0: reduce the 512 per-block emission partials (published by the
    // first FSTEP's barrier; consumed only in the tail)
    if (c == 0) {
        float sx = waveSumF(SumAuxArr[tid]);
        if (lane == 0) saux8[wv] = sx;
    }

    // ---- init beta at t = tw0 ----
    double OFF = 0.0;
    float nu0, nu1, nu2, nu3;
    {
        uintx2 p0 = *(const uintx2*)(P + (size_t)tw0 * SD + tid * 4);
        if (c == 0) {   // exact: beta_0 = P_0 * pi
            float lp23 = logpi2[d2p] + logpi3[d3p];
            nu0 = bfl(p0.x) * __expf(logpi1[4 * q + 0] + lp23);
            nu1 = bfh(p0.x) * __expf(logpi1[4 * q + 1] + lp23);
            nu2 = bfl(p0.y) * __expf(logpi1[4 * q + 2] + lp23);
            nu3 = bfh(p0.y) * __expf(logpi1[4 * q + 3] + lp23);
        } else {        // warm-start: beta = P row (arbitrary positive scale)
            nu0 = bfl(p0.x); nu1 = bfh(p0.x);
            nu2 = bfl(p0.y); nu3 = bfh(p0.y);
        }
    }

    // 2-deep P prefetch
    uintx2 Pb0 = *(const uintx2*)(P + (size_t)(tw0 + 1) * SD + tid * 4);
    uintx2 Pb1 = *(const uintx2*)(P + (size_t)(tw0 + 2) * SD + tid * 4);

// One forward step. RESC: compile-time (apply inv + maybe log); on !RESC steps
// compute the per-wave max (wa) feeding the next RESC step. ACCF: runtime
// uniform bool (t > bAcc) gating OFF accumulation.
#define FSTEP(T, RESC, ACCF)                                                    \
{                                                                               \
    const int par = (T) & 1;                                                    \
    short* c1cur = c1b + (par << 11);                                           \
    {   /* Stage 1 from registers */                                            \
        short4v af = pk4(nu0, nu1, nu2, nu3);                                   \
        floatx4 s1 = {0.f, 0.f, 0.f, 0.f};                                      \
        s1 = MFMA16(af, bA1k, s1);                                              \
        ((uintx2*)(c1cur + oS1w))[0] =                                          \
            (uintx2){pkbf(s1[0], s1[1]), pkbf(s1[2], s1[3])};                   \
    }                                                                           \
    __syncthreads();                                                            \
    const int tn = ((T) + 2 < TMAX) ? (T) + 2 : TMAX - 1;                       \
    uintx2 Pb2 = *(const uintx2*)(P + (size_t)tn * SD + tid * 4);               \
    float inv = 1.f;                                                            \
    if (RESC) {                                                                 \
        float mp = waveMax64(wmA[lane & 7]);                                    \
        float mg = fmaxf(mp, 1e-30f);                                           \
        inv = __builtin_amdgcn_rcpf(mg);                                        \
        if ((ACCF) && tid == 0) OFF += (double)__logf(mg);                      \
    }                                                                           \
    {   /* Stage 2+3 fused */                                                   \
        floatx4 a0 = {0.f, 0.f, 0.f, 0.f};                                      \
        floatx4 a1 = {0.f, 0.f, 0.f, 0.f};                                      \
        a0 = MFMA32(*(const short8*)(c1cur + o23[0]), bK[0], a0);               \
        a1 = MFMA32(*(const short8*)(c1cur + o23[1]), bK[1], a1);               \
        a0 = MFMA32(*(const short8*)(c1cur + o23[2]), bK[2], a0);               \
        a1 = MFMA32(*(const short8*)(c1cur + o23[3]), bK[3], a1);               \
        floatx4 acc = a0 + a1;                                                  \
        if (RESC) {                                                             \
            nu0 = bfl(Pb0.x) * acc[0] * inv;                                    \
            nu1 = bfh(Pb0.x) * acc[1] * inv;                                    \
            nu2 = bfl(Pb0.y) * acc[2] * inv;                                    \
            nu3 = bfh(Pb0.y) * acc[3] * inv;                                    \
        } else {                                                                \
            nu0 = bfl(Pb0.x) * acc[0];                                          \
            nu1 = bfh(Pb0.x) * acc[1];                                          \
            nu2 = bfl(Pb0.y) * acc[2];                                          \
            nu3 = bfh(Pb0.y) * acc[3];                                          \
            float wa = waveMax64(fmaxf(fmaxf(nu0, nu1), fmaxf(nu2, nu3)));      \
            if (lane == 0) wmA[wv] = wa;                                        \
        }                                                                       \
    }                                                                           \
    Pb0 = Pb1; Pb1 = Pb2;                                                       \
}

    // steps tw0+1 .. tEnd-1; first and last are odd (tw0, tEnd, bAcc all even)
    FSTEP(tw0 + 1, false, false);
    for (int te = tw0 + 2; te < tEnd; te += 2) {
        const bool accf = te > bAcc;
        FSTEP(te, true, accf);
        FSTEP(te + 1, false, false);
    }
#undef FSTEP

    __syncthreads();

    if (c == CHK - 1) {
        float su = waveSumF(nu0 + nu1 + nu2 + nu3);
        if (lane == 0) sred[wv] = su;
        __syncthreads();
        if (tid == 0) {
            float tot = 0.f;
            #pragma unroll
            for (int i = 0; i < 8; ++i) tot += sred[i];
            OFF += (double)__logf(tot);
            atomicAdd(out, (float)OFF);
        }
    } else {
        if (tid == 0) {
            float mp = wmA[0];
            #pragma unroll
            for (int i = 1; i < 8; ++i) mp = fmaxf(mp, wmA[i]);
            OFF += (double)__logf(fmaxf(mp, 1e-30f));
            if (c == 0) {
                float sa = 0.f;
                #pragma unroll
                for (int i = 0; i < 8; ++i) sa += saux8[i];
                OFF += (double)sa;
            }
            atomicAdd(out, (float)OFF);
        }
    }
}

extern "C" void kernel_launch(void* const* d_in, const int* in_sizes, int n_in,
                              void* d_out, int out_size, void* d_ws, size_t ws_size,
                              hipStream_t stream) {
    const int*   x      = (const int*)  d_in[0];
    const float* lam1   = (const float*)d_in[1];
    const float* lam2   = (const float*)d_in[2];
    const float* lam3   = (const float*)d_in[3];
    const float* logA1  = (const float*)d_in[4];
    const float* logA2  = (const float*)d_in[5];
    const float* logA3  = (const float*)d_in[6];
    const float* logpi1 = (const float*)d_in[7];
    const float* logpi2 = (const float*)d_in[8];
    const float* logpi3 = (const float*)d_in[9];
    float* out = (float*)d_out;

    // ws: [SumAuxArr: 512 floats (2KB), pad to 4KB] [P_perm: TMAX*2048*2B = 64MB]
    float*  SumAuxArr = (float*)d_ws;
    ushort* P         = (ushort*)((char*)d_ws + 4096);

    // no memsets: out zeroed by emP block 0; SumAuxArr fully overwritten by
    // emP plain stores (one per block, 512 blocks == array size).
    emP_kernel <<<dim3(TMAX / EROWS), dim3(512), 0, stream>>>(
        x, lam1, lam2, lam3, P, SumAuxArr, out);
    fhmm_chunk_kernel<<<dim3(CHK), dim3(512), 0, stream>>>(
        P, SumAuxArr, logA1, logA2, logA3, logpi1, logpi2, logpi3, out);
}

// Round 9
// 159.119 us; speedup vs baseline: 1.2994x; 1.0033x over previous
//
#include <hip/hip_runtime.h>
#include <math.h>

#define TMAX 16384
#define MDIM 16
#define SD   2048
#define CHK  1024    // number of parallel chunks (= 256 CU x 4 blocks, exact fill)
#define CLEN 16      // steps per chunk (CHK*CLEN == TMAX)
#define WUP  16      // warmup steps per chunk (fast-mixing softmax transitions)
#define EROWS 32     // t-rows per emP block

typedef unsigned int  uint;
typedef unsigned short ushort;
typedef __attribute__((ext_vector_type(8))) short short8;
typedef __attribute__((ext_vector_type(4))) short short4v;
typedef __attribute__((ext_vector_type(4))) float floatx4;
typedef __attribute__((ext_vector_type(2))) uint uintx2;

// ---- DPP-based full-wave (64-lane) max ----
template<int CTRL>
__device__ __forceinline__ float fmax_dpp(float v) {
    int o = __builtin_amdgcn_update_dpp(__float_as_int(v), __float_as_int(v),
                                        CTRL, 0xf, 0xf, false);
    return fmaxf(v, __int_as_float(o));
}
__device__ __forceinline__ float waveMax64(float v) {
    v = fmax_dpp<0x111>(v);
    v = fmax_dpp<0x112>(v);
    v = fmax_dpp<0x114>(v);
    v = fmax_dpp<0x118>(v);
    v = fmax_dpp<0x142>(v);
    v = fmax_dpp<0x143>(v);
    return __int_as_float(__builtin_amdgcn_readlane(__float_as_int(v), 63));
}
__device__ __forceinline__ float waveSumF(float v) {
    #pragma unroll
    for (int o = 32; o > 0; o >>= 1) v += __shfl_xor(v, o, 64);
    return v;
}
__device__ __forceinline__ double waveSumD(double v) {
    #pragma unroll
    for (int o = 32; o > 0; o >>= 1) v += __shfl_xor(v, o, 64);
    return v;
}

// bf16 helpers (RNE emulation — bit-exact, harness-proven)
__device__ __forceinline__ short f2bfs(float f) {
    uint u = __float_as_uint(f);
    return (short)((u + 0x7FFFu + ((u >> 16) & 1u)) >> 16);
}
__device__ __forceinline__ uint pkbf(float a, float b) {
    uint ua = __float_as_uint(a), ub = __float_as_uint(b);
    ua = (ua + 0x7FFFu + ((ua >> 16) & 1u)) >> 16;
    ub = (ub + 0x7FFFu + ((ub >> 16) & 1u)) & 0xFFFF0000u;
    return ua | ub;
}
__device__ __forceinline__ short4v pk4(float a, float b, float c, float d) {
    short4v r;
    r[0] = f2bfs(a); r[1] = f2bfs(b); r[2] = f2bfs(c); r[3] = f2bfs(d);
    return r;
}
__device__ __forceinline__ float bfl(uint u) { return __uint_as_float(u << 16); }
__device__ __forceinline__ float bfh(uint u) { return __uint_as_float(u & 0xFFFF0000u); }

// K=16 bf16 MFMA
#if __has_builtin(__builtin_amdgcn_mfma_f32_16x16x16bf16_1k)
#define MFMA16(a, b, c) __builtin_amdgcn_mfma_f32_16x16x16bf16_1k(a, b, c, 0, 0, 0)
#else
__device__ __forceinline__ floatx4 mfma16_asm(short4v a, short4v b, floatx4 c) {
    asm volatile("v_mfma_f32_16x16x16_bf16 %0, %1, %2, %0\n\t"
                 "s_nop 7\n\ts_nop 7"
                 : "+v"(c) : "v"(a), "v"(b));
    return c;
}
#define MFMA16(a, b, c) mfma16_asm(a, b, c)
#endif
#define MFMA32(a, b, c) __builtin_amdgcn_mfma_f32_16x16x32_bf16(a, b, c, 0, 0, 0)

// ---- K2: SINGLE-PASS em-in-registers pre-pass. 512 blocks x 512 threads.
// [R7-verified: passed, emP dropped from 85us to <52.6us]
__global__ __launch_bounds__(512, 2)
void emP_kernel(const int* __restrict__ x,
                const float* __restrict__ lam1,
                const float* __restrict__ lam2,
                const float* __restrict__ lam3,
                ushort* __restrict__ P,
                float* __restrict__ SumAuxArr,
                float* __restrict__ out) {
    __shared__ float wmx[EROWS][8];
    __shared__ float DemS[EROWS];
    __shared__ float lgtbl[32];
    __shared__ __align__(16) float xfs[EROWS * MDIM];   // 512 floats
    __shared__ float lgred;
    const int tid = threadIdx.x, lane = tid & 63, wv = tid >> 6;
    const int q = lane >> 4, nn = lane & 15;
    const int d2 = 2 * wv + (nn >> 3);
    const int d3 = nn & 7;

    if (tid < 32) lgtbl[tid] = lgammaf((float)tid + 1.0f);
    if (tid == 0) lgred = 0.f;

    float llc[4][16], ls[4];
    #pragma unroll
    for (int j = 0; j < 4; ++j) {
        const int d1 = 4 * q + j;
        float sum = 0.f;
        #pragma unroll
        for (int m = 0; m < 16; ++m) {
            float la = lam1[d1 * 16 + m] + lam2[d2 * 16 + m] + lam3[d3 * 16 + m];
            sum += la;
            llc[j][m] = __logf(la);
        }
        ls[j] = sum;
    }

    const int t0 = blockIdx.x * EROWS;
    // one x element per thread: feeds BOTH the float table and the lgamma sum
    const int xv = x[t0 * MDIM + tid];
    xfs[tid] = (float)xv;
    __syncthreads();   // lgtbl + lgred + xfs ready
    {
        double lg = (double)lgtbl[xv & 31];
        lg = waveSumD(lg);
        if (lane == 0) atomicAdd(&lgred, (float)lg);
    }

    // ---- pass 1: em (kept in registers) + per-row wave maxima ----
    float em[EROWS][4];
    #pragma unroll
    for (int ti = 0; ti < EROWS; ++ti) {
        float xr[16];
        *(float4*)&xr[0]  = *(const float4*)&xfs[ti * 16 + 0];
        *(float4*)&xr[4]  = *(const float4*)&xfs[ti * 16 + 4];
        *(float4*)&xr[8]  = *(const float4*)&xfs[ti * 16 + 8];
        *(float4*)&xr[12] = *(const float4*)&xfs[ti * 16 + 12];
        float vm = -3.4e38f;
        #pragma unroll
        for (int j = 0; j < 4; ++j) {
            float d = 0.f;
            #pragma unroll
            for (int m = 0; m < 16; ++m) d = fmaf(xr[m], llc[j][m], d);
            em[ti][j] = d - ls[j];
            vm = fmaxf(vm, em[ti][j]);
        }
        vm = waveMax64(vm);
        if (lane == 0) wmx[ti][wv] = vm;     // wave-owned column, no race
    }
    __syncthreads();                          // all wmx published (+ lgred done)
    if (tid < 32) {
        float m = wmx[tid][0];
        #pragma unroll
        for (int i = 1; i < 8; ++i) m = fmaxf(m, wmx[tid][i]);
        DemS[tid] = m;
    }
    __syncthreads();                          // DemS ready

    // ---- pass 2: exp from registers, pack, streamed stores (no barriers) ----
    #pragma unroll
    for (int ti = 0; ti < EROWS; ++ti) {
        const float Dem = DemS[ti];
        uint2 w;
        w.x = pkbf(__expf(em[ti][0] - Dem), __expf(em[ti][1] - Dem));
        w.y = pkbf(__expf(em[ti][2] - Dem), __expf(em[ti][3] - Dem));
        *(uint2*)(P + (size_t)(t0 + ti) * SD + tid * 4) = w;
    }

    if (tid == 0) {
        double sumD = 0.0;
        #pragma unroll
        for (int i = 0; i < EROWS; ++i) sumD += (double)DemS[i];
        SumAuxArr[blockIdx.x] = (float)sumD - lgred;
        if (blockIdx.x == 0) out[0] = 0.f;   // ordered before fhmm (stream)
    }
}

// ---- K3: CHUNKED forward recurrence. grid = CHK(1024) blocks x 512 threads.
// R7 post-mortem: 63-step loop at 2 blocks/CU was latency-bound on the serial
// chain (2000 cyc/step, VALU 64%, HBM 16%). This round halves serial depth and
// doubles occupancy: CLEN=16, WUP=16 (softmax transitions mix fast; boundary
// error ~1e-4 << bf16 output ULP), CHK=1024 = 256CU x 4 blocks (VGPR=36 fits
// 8 waves/SIMD). FSTEP body and parity structure unchanged [R4-verified].
// Defer-rescale every 2 steps [R4-verified: passed, absmax 0.0].
__global__ __launch_bounds__(512, 4)
void fhmm_chunk_kernel(const ushort* __restrict__ P,
                       const float* __restrict__ SumAuxArr,
                       const float* __restrict__ logA1,
                       const float* __restrict__ logA2,
                       const float* __restrict__ logA3,
                       const float* __restrict__ logpi1,
                       const float* __restrict__ logpi2,
                       const float* __restrict__ logpi3,
                       float* __restrict__ out)
{
    __shared__ __align__(16) short c1b[2 * 2048];   // parity double buffer
    __shared__ float wmA[8];                        // odd steps write, even read
    __shared__ float sred[8];
    __shared__ float saux8[8];

    const int tid  = threadIdx.x;
    const int lane = tid & 63;
    const int wv   = tid >> 6;
    const int q    = lane >> 4;
    const int ml   = lane & 15;

    const int c    = blockIdx.x;
    const int tw0  = (c == 0) ? 0 : c * CLEN - WUP;
    const int tEnd = (c + 1) * CLEN;
    const int bAcc = c * CLEN;

    // S1 constants (K=16): B[k=p1=4q+j][n=d1'=ml] = exp(logA1[ml][4q+j])
    short4v bA1k;
    #pragma unroll
    for (int j = 0; j < 4; ++j)
        bA1k[j] = f2bfs(__expf(logA1[ml * 16 + 4 * q + j]));

    // S23 constants, 4 K-chunks: k' = 32jc + 8q + i -> p2 = 4jc+q, p3 = i
    const int d2p = 2 * wv + (ml >> 3);
    const int d3p = ml & 7;
    short8 bK[4];
    #pragma unroll
    for (int jc = 0; jc < 4; ++jc)
        #pragma unroll
        for (int i = 0; i < 8; ++i)
            bK[jc][i] = f2bfs(__expf(logA2[d2p * 16 + 4 * jc + q] + logA3[d3p * 8 + i]));

    // S1 D write offset into c1b[par]  [R9/R10-verified]
    const int oS1w = ml * 128 + ((((2 * wv + (q >> 1)) ^ ml) & 15) << 3) + 4 * (q & 1);
    // S23 A-frag offsets [R9/R10-verified]
    int o23[4];
    #pragma unroll
    for (int jc = 0; jc < 4; ++jc)
        o23[jc] = ml * 128 + ((((4 * jc + q) ^ ml) & 15) << 3);

    // chunk 0: reduce the 512 per-block emission partials (published by the
    // first FSTEP's barrier; consumed only in the tail). emP grid == 512.
    if (c == 0) {
        float sx = waveSumF(SumAuxArr[tid]);
        if (lane == 0) saux8[wv] = sx;
    }

    // ---- init beta at t = tw0 ----
    double OFF = 0.0;
    float nu0, nu1, nu2, nu3;
    {
        uintx2 p0 = *(const uintx2*)(P + (size_t)tw0 * SD + tid * 4);
        if (c == 0) {   // exact: beta_0 = P_0 * pi
            float lp23 = logpi2[d2p] + logpi3[d3p];
            nu0 = bfl(p0.x) * __expf(logpi1[4 * q + 0] + lp23);
            nu1 = bfh(p0.x) * __expf(logpi1[4 * q + 1] + lp23);
            nu2 = bfl(p0.y) * __expf(logpi1[4 * q + 2] + lp23);
            nu3 = bfh(p0.y) * __expf(logpi1[4 * q + 3] + lp23);
        } else {        // warm-start: beta = P row (arbitrary positive scale)
            nu0 = bfl(p0.x); nu1 = bfh(p0.x);
            nu2 = bfl(p0.y); nu3 = bfh(p0.y);
        }
    }

    // 2-deep P prefetch
    uintx2 Pb0 = *(const uintx2*)(P + (size_t)(tw0 + 1) * SD + tid * 4);
    uintx2 Pb1 = *(const uintx2*)(P + (size_t)(tw0 + 2) * SD + tid * 4);

// One forward step. RESC: compile-time (apply inv + maybe log); on !RESC steps
// compute the per-wave max (wa) feeding the next RESC step. ACCF: runtime
// uniform bool (t > bAcc) gating OFF accumulation.
#define FSTEP(T, RESC, ACCF)                                                    \
{                                                                               \
    const int par = (T) & 1;                                                    \
    short* c1cur = c1b + (par << 11);                                           \
    {   /* Stage 1 from registers */                                            \
        short4v af = pk4(nu0, nu1, nu2, nu3);                                   \
        floatx4 s1 = {0.f, 0.f, 0.f, 0.f};                                      \
        s1 = MFMA16(af, bA1k, s1);                                              \
        ((uintx2*)(c1cur + oS1w))[0] =                                          \
            (uintx2){pkbf(s1[0], s1[1]), pkbf(s1[2], s1[3])};                   \
    }                                                                           \
    __syncthreads();                                                            \
    const int tn = ((T) + 2 < TMAX) ? (T) + 2 : TMAX - 1;                       \
    uintx2 Pb2 = *(const uintx2*)(P + (size_t)tn * SD + tid * 4);               \
    float inv = 1.f;                                                            \
    if (RESC) {                                                                 \
        float mp = waveMax64(wmA[lane & 7]);                                    \
        float mg = fmaxf(mp, 1e-30f);                                           \
        inv = __builtin_amdgcn_rcpf(mg);                                        \
        if ((ACCF) && tid == 0) OFF += (double)__logf(mg);                      \
    }                                                                           \
    {   /* Stage 2+3 fused */                                                   \
        floatx4 a0 = {0.f, 0.f, 0.f, 0.f};                                      \
        floatx4 a1 = {0.f, 0.f, 0.f, 0.f};                                      \
        a0 = MFMA32(*(const short8*)(c1cur + o23[0]), bK[0], a0);               \
        a1 = MFMA32(*(const short8*)(c1cur + o23[1]), bK[1], a1);               \
        a0 = MFMA32(*(const short8*)(c1cur + o23[2]), bK[2], a0);               \
        a1 = MFMA32(*(const short8*)(c1cur + o23[3]), bK[3], a1);               \
        floatx4 acc = a0 + a1;                                                  \
        if (RESC) {                                                             \
            nu0 = bfl(Pb0.x) * acc[0] * inv;                                    \
            nu1 = bfh(Pb0.x) * acc[1] * inv;                                    \
            nu2 = bfl(Pb0.y) * acc[2] * inv;                                    \
            nu3 = bfh(Pb0.y) * acc[3] * inv;                                    \
        } else {                                                                \
            nu0 = bfl(Pb0.x) * acc[0];                                          \
            nu1 = bfh(Pb0.x) * acc[1];                                          \
            nu2 = bfl(Pb0.y) * acc[2];                                          \
            nu3 = bfh(Pb0.y) * acc[3];                                          \
            float wa = waveMax64(fmaxf(fmaxf(nu0, nu1), fmaxf(nu2, nu3)));      \
            if (lane == 0) wmA[wv] = wa;                                        \
        }                                                                       \
    }                                                                           \
    Pb0 = Pb1; Pb1 = Pb2;                                                       \
}

    // steps tw0+1 .. tEnd-1; first and last are odd (tw0, tEnd, bAcc all even)
    FSTEP(tw0 + 1, false, false);
    for (int te = tw0 + 2; te < tEnd; te += 2) {
        const bool accf = te > bAcc;
        FSTEP(te, true, accf);
        FSTEP(te + 1, false, false);
    }
#undef FSTEP

    __syncthreads();

    if (c == CHK - 1) {
        float su = waveSumF(nu0 + nu1 + nu2 + nu3);
        if (lane == 0) sred[wv] = su;
        __syncthreads();
        if (tid == 0) {
            float tot = 0.f;
            #pragma unroll
            for (int i = 0; i < 8; ++i) tot += sred[i];
            OFF += (double)__logf(tot);
            atomicAdd(out, (float)OFF);
        }
    } else {
        if (tid == 0) {
            float mp = wmA[0];
            #pragma unroll
            for (int i = 1; i < 8; ++i) mp = fmaxf(mp, wmA[i]);
            OFF += (double)__logf(fmaxf(mp, 1e-30f));
            if (c == 0) {
                float sa = 0.f;
                #pragma unroll
                for (int i = 0; i < 8; ++i) sa += saux8[i];
                OFF += (double)sa;
            }
            atomicAdd(out, (float)OFF);
        }
    }
}

extern "C" void kernel_launch(void* const* d_in, const int* in_sizes, int n_in,
                              void* d_out, int out_size, void* d_ws, size_t ws_size,
                              hipStream_t stream) {
    const int*   x      = (const int*)  d_in[0];
    const float* lam1   = (const float*)d_in[1];
    const float* lam2   = (const float*)d_in[2];
    const float* lam3   = (const float*)d_in[3];
    const float* logA1  = (const float*)d_in[4];
    const float* logA2  = (const float*)d_in[5];
    const float* logA3  = (const float*)d_in[6];
    const float* logpi1 = (const float*)d_in[7];
    const float* logpi2 = (const float*)d_in[8];
    const float* logpi3 = (const float*)d_in[9];
    float* out = (float*)d_out;

    // ws: [SumAuxArr: 512 floats (2KB), pad to 4KB] [P_perm: TMAX*2048*2B = 64MB]
    float*  SumAuxArr = (float*)d_ws;
    ushort* P         = (ushort*)((char*)d_ws + 4096);

    // no memsets: out zeroed by emP block 0; SumAuxArr fully overwritten by
    // emP plain stores (one per block, 512 blocks == array size).
    emP_kernel <<<dim3(TMAX / EROWS), dim3(512), 0, stream>>>(
        x, lam1, lam2, lam3, P, SumAuxArr, out);
    fhmm_chunk_kernel<<<dim3(CHK), dim3(512), 0, stream>>>(
        P, SumAuxArr, logA1, logA2, logA3, logpi1, logpi2, logpi3, out);
}

// Round 10
// 156.238 us; speedup vs baseline: 1.3234x; 1.0184x over previous
//
#include <hip/hip_runtime.h>
#include <math.h>

#define TMAX 16384
#define MDIM 16
#define SD   2048
#define CLEN 16      // steps per chunk
#define WUP  16      // warmup steps per chunk (R9-verified: passed, absmax 0.0)
#define CHKB 512     // fhmm blocks; each runs TWO chunks (cA=2b, cB=2b+1)
#define NS   (CLEN + WUP - 1)   // 31 steps per chunk (odd; s=1 prologue + 15 pairs)
#define EROWS 32     // t-rows per emP block

typedef unsigned int  uint;
typedef unsigned short ushort;
typedef __attribute__((ext_vector_type(8))) short short8;
typedef __attribute__((ext_vector_type(4))) short short4v;
typedef __attribute__((ext_vector_type(4))) float floatx4;
typedef __attribute__((ext_vector_type(2))) uint uintx2;

// ---- DPP-based full-wave (64-lane) max ----
template<int CTRL>
__device__ __forceinline__ float fmax_dpp(float v) {
    int o = __builtin_amdgcn_update_dpp(__float_as_int(v), __float_as_int(v),
                                        CTRL, 0xf, 0xf, false);
    return fmaxf(v, __int_as_float(o));
}
__device__ __forceinline__ float waveMax64(float v) {
    v = fmax_dpp<0x111>(v);
    v = fmax_dpp<0x112>(v);
    v = fmax_dpp<0x114>(v);
    v = fmax_dpp<0x118>(v);
    v = fmax_dpp<0x142>(v);
    v = fmax_dpp<0x143>(v);
    return __int_as_float(__builtin_amdgcn_readlane(__float_as_int(v), 63));
}
__device__ __forceinline__ float waveSumF(float v) {
    #pragma unroll
    for (int o = 32; o > 0; o >>= 1) v += __shfl_xor(v, o, 64);
    return v;
}
__device__ __forceinline__ double waveSumD(double v) {
    #pragma unroll
    for (int o = 32; o > 0; o >>= 1) v += __shfl_xor(v, o, 64);
    return v;
}

// bf16 helpers (RNE emulation — bit-exact, harness-proven)
__device__ __forceinline__ short f2bfs(float f) {
    uint u = __float_as_uint(f);
    return (short)((u + 0x7FFFu + ((u >> 16) & 1u)) >> 16);
}
__device__ __forceinline__ uint pkbf(float a, float b) {
    uint ua = __float_as_uint(a), ub = __float_as_uint(b);
    ua = (ua + 0x7FFFu + ((ua >> 16) & 1u)) >> 16;
    ub = (ub + 0x7FFFu + ((ub >> 16) & 1u)) & 0xFFFF0000u;
    return ua | ub;
}
__device__ __forceinline__ short4v pk4(float a, float b, float c, float d) {
    short4v r;
    r[0] = f2bfs(a); r[1] = f2bfs(b); r[2] = f2bfs(c); r[3] = f2bfs(d);
    return r;
}
__device__ __forceinline__ float bfl(uint u) { return __uint_as_float(u << 16); }
__device__ __forceinline__ float bfh(uint u) { return __uint_as_float(u & 0xFFFF0000u); }

// K=16 bf16 MFMA
#if __has_builtin(__builtin_amdgcn_mfma_f32_16x16x16bf16_1k)
#define MFMA16(a, b, c) __builtin_amdgcn_mfma_f32_16x16x16bf16_1k(a, b, c, 0, 0, 0)
#else
__device__ __forceinline__ floatx4 mfma16_asm(short4v a, short4v b, floatx4 c) {
    asm volatile("v_mfma_f32_16x16x16_bf16 %0, %1, %2, %0\n\t"
                 "s_nop 7\n\ts_nop 7"
                 : "+v"(c) : "v"(a), "v"(b));
    return c;
}
#define MFMA16(a, b, c) mfma16_asm(a, b, c)
#endif
#define MFMA32(a, b, c) __builtin_amdgcn_mfma_f32_16x16x32_bf16(a, b, c, 0, 0, 0)

// ---- K2: SINGLE-PASS em-in-registers pre-pass. 512 blocks x 512 threads.
// [R7-verified: passed, emP dropped from 85us to <52.6us] — unchanged.
__global__ __launch_bounds__(512, 2)
void emP_kernel(const int* __restrict__ x,
                const float* __restrict__ lam1,
                const float* __restrict__ lam2,
                const float* __restrict__ lam3,
                ushort* __restrict__ P,
                float* __restrict__ SumAuxArr,
                float* __restrict__ out) {
    __shared__ float wmx[EROWS][8];
    __shared__ float DemS[EROWS];
    __shared__ float lgtbl[32];
    __shared__ __align__(16) float xfs[EROWS * MDIM];   // 512 floats
    __shared__ float lgred;
    const int tid = threadIdx.x, lane = tid & 63, wv = tid >> 6;
    const int q = lane >> 4, nn = lane & 15;
    const int d2 = 2 * wv + (nn >> 3);
    const int d3 = nn & 7;

    if (tid < 32) lgtbl[tid] = lgammaf((float)tid + 1.0f);
    if (tid == 0) lgred = 0.f;

    float llc[4][16], ls[4];
    #pragma unroll
    for (int j = 0; j < 4; ++j) {
        const int d1 = 4 * q + j;
        float sum = 0.f;
        #pragma unroll
        for (int m = 0; m < 16; ++m) {
            float la = lam1[d1 * 16 + m] + lam2[d2 * 16 + m] + lam3[d3 * 16 + m];
            sum += la;
            llc[j][m] = __logf(la);
        }
        ls[j] = sum;
    }

    const int t0 = blockIdx.x * EROWS;
    const int xv = x[t0 * MDIM + tid];
    xfs[tid] = (float)xv;
    __syncthreads();   // lgtbl + lgred + xfs ready
    {
        double lg = (double)lgtbl[xv & 31];
        lg = waveSumD(lg);
        if (lane == 0) atomicAdd(&lgred, (float)lg);
    }

    // ---- pass 1: em (kept in registers) + per-row wave maxima ----
    float em[EROWS][4];
    #pragma unroll
    for (int ti = 0; ti < EROWS; ++ti) {
        float xr[16];
        *(float4*)&xr[0]  = *(const float4*)&xfs[ti * 16 + 0];
        *(float4*)&xr[4]  = *(const float4*)&xfs[ti * 16 + 4];
        *(float4*)&xr[8]  = *(const float4*)&xfs[ti * 16 + 8];
        *(float4*)&xr[12] = *(const float4*)&xfs[ti * 16 + 12];
        float vm = -3.4e38f;
        #pragma unroll
        for (int j = 0; j < 4; ++j) {
            float d = 0.f;
            #pragma unroll
            for (int m = 0; m < 16; ++m) d = fmaf(xr[m], llc[j][m], d);
            em[ti][j] = d - ls[j];
            vm = fmaxf(vm, em[ti][j]);
        }
        vm = waveMax64(vm);
        if (lane == 0) wmx[ti][wv] = vm;     // wave-owned column, no race
    }
    __syncthreads();
    if (tid < 32) {
        float m = wmx[tid][0];
        #pragma unroll
        for (int i = 1; i < 8; ++i) m = fmaxf(m, wmx[tid][i]);
        DemS[tid] = m;
    }
    __syncthreads();

    // ---- pass 2: exp from registers, pack, streamed stores (no barriers) ----
    #pragma unroll
    for (int ti = 0; ti < EROWS; ++ti) {
        const float Dem = DemS[ti];
        uint2 w;
        w.x = pkbf(__expf(em[ti][0] - Dem), __expf(em[ti][1] - Dem));
        w.y = pkbf(__expf(em[ti][2] - Dem), __expf(em[ti][3] - Dem));
        *(uint2*)(P + (size_t)(t0 + ti) * SD + tid * 4) = w;
    }

    if (tid == 0) {
        double sumD = 0.0;
        #pragma unroll
        for (int i = 0; i < EROWS; ++i) sumD += (double)DemS[i];
        SumAuxArr[blockIdx.x] = (float)sumD - lgred;
        if (blockIdx.x == 0) out[0] = 0.f;
    }
}

// ---- K3: TWO-CHUNK interleaved forward recurrence. grid = CHKB(512) x 512.
// R9 post-mortem: occupancy can't hide the ~2000-cyc per-step serial chain
// (pk4->MFMA16->ds_write->barrier->ds_read(~120cy)->MFMA32->waveMax); doubling
// blocks/CU doubled per-step cost. Fix = ILP: each block runs TWO independent
// chunks (cA=2b, cB=2b+1), steps interleaved in one super-step with a SINGLE
// shared barrier; chain B's compute hides chain A's LDS/barrier latency.
// Per-chunk arithmetic identical to R4/R9-verified template (both chunks share
// bA1k/bK/o23 constants). 2 blocks/CU, LDS 16.5KB, <=128 VGPR.
__global__ __launch_bounds__(512, 4)
void fhmm_chunk_kernel(const ushort* __restrict__ P,
                       const float* __restrict__ SumAuxArr,
                       const float* __restrict__ logA1,
                       const float* __restrict__ logA2,
                       const float* __restrict__ logA3,
                       const float* __restrict__ logpi1,
                       const float* __restrict__ logpi2,
                       const float* __restrict__ logpi3,
                       float* __restrict__ out)
{
    __shared__ __align__(16) short c1bA[2 * 2048];  // chunk A parity double buffer
    __shared__ __align__(16) short c1bB[2 * 2048];  // chunk B parity double buffer
    __shared__ float wmAA[8], wmAB[8];              // odd steps write, even read
    __shared__ float sred[8];
    __shared__ float saux8[8];

    const int tid  = threadIdx.x;
    const int lane = tid & 63;
    const int wv   = tid >> 6;
    const int q    = lane >> 4;
    const int ml   = lane & 15;

    const int b   = blockIdx.x;
    // chunk A = 2b (warm-start at 32b-16, except b=0: exact init at 0)
    // chunk B = 2b+1 (warm-start at 32b); both run NS=31 steps, same t-parity
    const int tA0 = (b == 0) ? 0 : 32 * b - 16;
    const int tB0 = 32 * b;

    // S1 constants (K=16): B[k=p1=4q+j][n=d1'=ml] = exp(logA1[ml][4q+j])
    short4v bA1k;
    #pragma unroll
    for (int j = 0; j < 4; ++j)
        bA1k[j] = f2bfs(__expf(logA1[ml * 16 + 4 * q + j]));

    // S23 constants, 4 K-chunks: k' = 32jc + 8q + i -> p2 = 4jc+q, p3 = i
    const int d2p = 2 * wv + (ml >> 3);
    const int d3p = ml & 7;
    short8 bK[4];
    #pragma unroll
    for (int jc = 0; jc < 4; ++jc)
        #pragma unroll
        for (int i = 0; i < 8; ++i)
            bK[jc][i] = f2bfs(__expf(logA2[d2p * 16 + 4 * jc + q] + logA3[d3p * 8 + i]));

    // S1 D write offset  [R9/R10-verified]
    const int oS1w = ml * 128 + ((((2 * wv + (q >> 1)) ^ ml) & 15) << 3) + 4 * (q & 1);
    // S23 A-frag offsets [R9/R10-verified]
    int o23[4];
    #pragma unroll
    for (int jc = 0; jc < 4; ++jc)
        o23[jc] = ml * 128 + ((((4 * jc + q) ^ ml) & 15) << 3);

    // block 0: reduce the 512 per-block emission partials (consumed in tail)
    if (b == 0) {
        float sx = waveSumF(SumAuxArr[tid]);
        if (lane == 0) saux8[wv] = sx;
    }

    // ---- init both chunks ----
    double OFF = 0.0;     // combined A+B offset (tid0 only meaningful)
    float nuA[4], nuB[4];
    {
        uintx2 p0 = *(const uintx2*)(P + (size_t)tA0 * SD + tid * 4);
        if (b == 0) {   // exact: beta_0 = P_0 * pi
            float lp23 = logpi2[d2p] + logpi3[d3p];
            nuA[0] = bfl(p0.x) * __expf(logpi1[4 * q + 0] + lp23);
            nuA[1] = bfh(p0.x) * __expf(logpi1[4 * q + 1] + lp23);
            nuA[2] = bfl(p0.y) * __expf(logpi1[4 * q + 2] + lp23);
            nuA[3] = bfh(p0.y) * __expf(logpi1[4 * q + 3] + lp23);
        } else {
            nuA[0] = bfl(p0.x); nuA[1] = bfh(p0.x);
            nuA[2] = bfl(p0.y); nuA[3] = bfh(p0.y);
        }
    }
    {
        uintx2 p0 = *(const uintx2*)(P + (size_t)tB0 * SD + tid * 4);
        nuB[0] = bfl(p0.x); nuB[1] = bfh(p0.x);
        nuB[2] = bfl(p0.y); nuB[3] = bfh(p0.y);
    }

    // 2-deep P prefetch per chunk
    uintx2 PbA0 = *(const uintx2*)(P + (size_t)(tA0 + 1) * SD + tid * 4);
    uintx2 PbA1 = *(const uintx2*)(P + (size_t)(tA0 + 2) * SD + tid * 4);
    uintx2 PbB0 = *(const uintx2*)(P + (size_t)(tB0 + 1) * SD + tid * 4);
    uintx2 PbB1 = *(const uintx2*)(P + (size_t)(tB0 + 2) * SD + tid * 4);

// One SUPER-step: both chunks' step s, ONE barrier. RESC compile-time;
// ACCFA/ACCFB runtime-uniform accumulate guards.
#define SSTEP(S, RESC, ACCFA, ACCFB)                                            \
{                                                                               \
    const int par = (S) & 1;    /* tA0,tB0 even -> t parity == s parity */      \
    short* cAq = c1bA + (par << 11);                                            \
    short* cBq = c1bB + (par << 11);                                            \
    {   /* Stage 1, both chunks, from registers */                              \
        short4v afA = pk4(nuA[0], nuA[1], nuA[2], nuA[3]);                      \
        short4v afB = pk4(nuB[0], nuB[1], nuB[2], nuB[3]);                      \
        floatx4 sA = {0.f, 0.f, 0.f, 0.f};                                      \
        floatx4 sB = {0.f, 0.f, 0.f, 0.f};                                      \
        sA = MFMA16(afA, bA1k, sA);                                             \
        sB = MFMA16(afB, bA1k, sB);                                             \
        ((uintx2*)(cAq + oS1w))[0] = (uintx2){pkbf(sA[0], sA[1]), pkbf(sA[2], sA[3])}; \
        ((uintx2*)(cBq + oS1w))[0] = (uintx2){pkbf(sB[0], sB[1]), pkbf(sB[2], sB[3])}; \
    }                                                                           \
    __syncthreads();                                                            \
    const int tnA = (tA0 + (S) + 2 < TMAX) ? tA0 + (S) + 2 : TMAX - 1;          \
    const int tnB = (tB0 + (S) + 2 < TMAX) ? tB0 + (S) + 2 : TMAX - 1;          \
    uintx2 PbA2 = *(const uintx2*)(P + (size_t)tnA * SD + tid * 4);             \
    uintx2 PbB2 = *(const uintx2*)(P + (size_t)tnB * SD + tid * 4);             \
    float invA = 1.f, invB = 1.f;                                               \
    if (RESC) {                                                                 \
        float mpA = waveMax64(wmAA[lane & 7]);                                  \
        float mpB = waveMax64(wmAB[lane & 7]);                                  \
        float mgA = fmaxf(mpA, 1e-30f);                                         \
        float mgB = fmaxf(mpB, 1e-30f);                                         \
        invA = __builtin_amdgcn_rcpf(mgA);                                      \
        invB = __builtin_amdgcn_rcpf(mgB);                                      \
        if (tid == 0) {                                                         \
            if (ACCFA) OFF += (double)__logf(mgA);                              \
            if (ACCFB) OFF += (double)__logf(mgB);                              \
        }                                                                       \
    }                                                                           \
    {   /* Stage 2+3, both chunks: issue all 8 reads, then 8 MFMAs */           \
        short8 fA0 = *(const short8*)(cAq + o23[0]);                            \
        short8 fA1 = *(const short8*)(cAq + o23[1]);                            \
        short8 fA2 = *(const short8*)(cAq + o23[2]);                            \
        short8 fA3 = *(const short8*)(cAq + o23[3]);                            \
        short8 fB0 = *(const short8*)(cBq + o23[0]);                            \
        short8 fB1 = *(const short8*)(cBq + o23[1]);                            \
        short8 fB2 = *(const short8*)(cBq + o23[2]);                            \
        short8 fB3 = *(const short8*)(cBq + o23[3]);                            \
        floatx4 aA0 = {0.f, 0.f, 0.f, 0.f};                                     \
        floatx4 aA1 = {0.f, 0.f, 0.f, 0.f};                                     \
        floatx4 aB0 = {0.f, 0.f, 0.f, 0.f};                                     \
        floatx4 aB1 = {0.f, 0.f, 0.f, 0.f};                                     \
        aA0 = MFMA32(fA0, bK[0], aA0);  aB0 = MFMA32(fB0, bK[0], aB0);          \
        aA1 = MFMA32(fA1, bK[1], aA1);  aB1 = MFMA32(fB1, bK[1], aB1);          \
        aA0 = MFMA32(fA2, bK[2], aA0);  aB0 = MFMA32(fB2, bK[2], aB0);          \
        aA1 = MFMA32(fA3, bK[3], aA1);  aB1 = MFMA32(fB3, bK[3], aB1);          \
        floatx4 accA = aA0 + aA1;                                               \
        floatx4 accB = aB0 + aB1;                                               \
        if (RESC) {                                                             \
            nuA[0] = bfl(PbA0.x) * accA[0] * invA;                              \
            nuA[1] = bfh(PbA0.x) * accA[1] * invA;                              \
            nuA[2] = bfl(PbA0.y) * accA[2] * invA;                              \
            nuA[3] = bfh(PbA0.y) * accA[3] * invA;                              \
            nuB[0] = bfl(PbB0.x) * accB[0] * invB;                              \
            nuB[1] = bfh(PbB0.x) * accB[1] * invB;                              \
            nuB[2] = bfl(PbB0.y) * accB[2] * invB;                              \
            nuB[3] = bfh(PbB0.y) * accB[3] * invB;                              \
        } else {                                                                \
            nuA[0] = bfl(PbA0.x) * accA[0];                                     \
            nuA[1] = bfh(PbA0.x) * accA[1];                                     \
            nuA[2] = bfl(PbA0.y) * accA[2];                                     \
            nuA[3] = bfh(PbA0.y) * accA[3];                                     \
            nuB[0] = bfl(PbB0.x) * accB[0];                                     \
            nuB[1] = bfh(PbB0.x) * accB[1];                                     \
            nuB[2] = bfl(PbB0.y) * accB[2];                                     \
            nuB[3] = bfh(PbB0.y) * accB[3];                                     \
            float waA = waveMax64(fmaxf(fmaxf(nuA[0], nuA[1]), fmaxf(nuA[2], nuA[3]))); \
            float waB = waveMax64(fmaxf(fmaxf(nuB[0], nuB[1]), fmaxf(nuB[2], nuB[3]))); \
            if (lane == 0) { wmAA[wv] = waA; wmAB[wv] = waB; }                  \
        }                                                                       \
    }                                                                           \
    PbA0 = PbA1; PbA1 = PbA2; PbB0 = PbB1; PbB1 = PbB2;                         \
}

    // s = 1 .. NS(=31); first/last odd (non-RESC), RESC on even s.
    // accfA: chunk 0 accumulates always; others when s > WUP. accfB: s > WUP.
    SSTEP(1, false, false, false);
    for (int s = 2; s < NS; s += 2) {
        const bool accfA = (b == 0) || (s > WUP);
        const bool accfB = (s > WUP);
        SSTEP(s, true, accfA, accfB);
        SSTEP(s + 1, false, false, false);
    }
#undef SSTEP

    __syncthreads();

    if (b == CHKB - 1) {     // chunk B here is the LAST chunk: sum path
        float su = waveSumF(nuB[0] + nuB[1] + nuB[2] + nuB[3]);
        if (lane == 0) sred[wv] = su;
        __syncthreads();
        if (tid == 0) {
            float mpA = wmAA[0];
            #pragma unroll
            for (int i = 1; i < 8; ++i) mpA = fmaxf(mpA, wmAA[i]);
            OFF += (double)__logf(fmaxf(mpA, 1e-30f));
            float tot = 0.f;
            #pragma unroll
            for (int i = 0; i < 8; ++i) tot += sred[i];
            OFF += (double)__logf(tot);
            atomicAdd(out, (float)OFF);
        }
    } else {
        if (tid == 0) {
            float mpA = wmAA[0], mpB = wmAB[0];
            #pragma unroll
            for (int i = 1; i < 8; ++i) {
                mpA = fmaxf(mpA, wmAA[i]);
                mpB = fmaxf(mpB, wmAB[i]);
            }
            OFF += (double)__logf(fmaxf(mpA, 1e-30f));
            OFF += (double)__logf(fmaxf(mpB, 1e-30f));
            if (b == 0) {
                float sa = 0.f;
                #pragma unroll
                for (int i = 0; i < 8; ++i) sa += saux8[i];
                OFF += (double)sa;
            }
            atomicAdd(out, (float)OFF);
        }
    }
}

extern "C" void kernel_launch(void* const* d_in, const int* in_sizes, int n_in,
                              void* d_out, int out_size, void* d_ws, size_t ws_size,
                              hipStream_t stream) {
    const int*   x      = (const int*)  d_in[0];
    const float* lam1   = (const float*)d_in[1];
    const float* lam2   = (const float*)d_in[2];
    const float* lam3   = (const float*)d_in[3];
    const float* logA1  = (const float*)d_in[4];
    const float* logA2  = (const float*)d_in[5];
    const float* logA3  = (const float*)d_in[6];
    const float* logpi1 = (const float*)d_in[7];
    const float* logpi2 = (const float*)d_in[8];
    const float* logpi3 = (const float*)d_in[9];
    float* out = (float*)d_out;

    // ws: [SumAuxArr: 512 floats (2KB), pad to 4KB] [P_perm: TMAX*2048*2B = 64MB]
    float*  SumAuxArr = (float*)d_ws;
    ushort* P         = (ushort*)((char*)d_ws + 4096);

    // no memsets: out zeroed by emP block 0; SumAuxArr fully overwritten by
    // emP plain stores (one per block, 512 blocks == array size).
    emP_kernel <<<dim3(TMAX / EROWS), dim3(512), 0, stream>>>(
        x, lam1, lam2, lam3, P, SumAuxArr, out);
    fhmm_chunk_kernel<<<dim3(CHKB), dim3(512), 0, stream>>>(
        P, SumAuxArr, logA1, logA2, logA3, logpi1, logpi2, logpi3, out);
}